// Round 3
// baseline (83.088 us; speedup 1.0000x reference)
//
#include <hip/hip_runtime.h>
#include <math.h>

#define BB 16
#define TT 60
#define NN 196
#define CC 512
#define HH 4
#define DD 128
#define TOPM 10
#define FRONT_BLOCKS 128

// ws layout (floats): [0..63] counters (ints, 64B-spaced); 64: q(512);
// 576: qW(2048); 2624: sc(784); 3408: p(int)
#define WS_Q   64
#define WS_QW  576
#define WS_SC  2624
#define WS_P   3408

__device__ __forceinline__ void grid_barrier(int* cnt, int target) {
    __threadfence();                       // make this block's writes visible (device scope)
    __syncthreads();                       // all threads of block done + fenced
    if (threadIdx.x == 0) {
        __hip_atomic_fetch_add(cnt, 1, __ATOMIC_RELEASE, __HIP_MEMORY_SCOPE_AGENT);
        while (__hip_atomic_load(cnt, __ATOMIC_ACQUIRE, __HIP_MEMORY_SCOPE_AGENT) < target) {}
    }
    __syncthreads();
    __threadfence();                       // acquire for all threads of block
}

// ---------------------------------------------------------------------------
// Fused front: 128 blocks x 256 threads, inc-then-spin barriers between phases.
// A: q[e] = qst[0,:]·Wq[e,:] + bq[e]           (wave per e, 4 waves/block)
// B: qW[h,c] = sum_d q[h*128+d]*Wk[h*128+d,c]  (16 outputs/block, d split 16-way)
// C: sc[h,n] = scale * qW[h,:]·x[0,0,n,:]      (wave per h, 1-2 n per block)
// tail (last block through C): softmax/mean/top-10 -> p
// (bk bias dropped: per-head constant cancels in softmax over n)
// ---------------------------------------------------------------------------
__global__ void __launch_bounds__(256) k_front(
        const float* __restrict__ x, const float* __restrict__ qst,
        const float* __restrict__ Wq, const float* __restrict__ bq,
        const float* __restrict__ Wk, float* __restrict__ ws) {
    int* cnt = (int*)ws;
    float* q  = ws + WS_Q;
    float* qW = ws + WS_QW;
    float* sc = ws + WS_SC;

    int b = blockIdx.x, tid = threadIdx.x;
    int wv = tid >> 6, lane = tid & 63;

    // ---- Phase A: q ----
    {
        int e = b * 4 + wv;                                    // 0..511
        const float4* row = (const float4*)(Wq + (size_t)e * CC);
        const float4* qs  = (const float4*)qst;                // b=0 row
        float acc = 0.f;
#pragma unroll
        for (int j = 0; j < 2; ++j) {
            int c4 = lane * 2 + j;
            float4 w = row[c4], xv = qs[c4];
            acc += w.x * xv.x + w.y * xv.y + w.z * xv.z + w.w * xv.w;
        }
#pragma unroll
        for (int off = 32; off; off >>= 1) acc += __shfl_xor(acc, off);
        if (lane == 0) q[e] = acc + bq[e];
    }
    grid_barrier(cnt + 0, FRONT_BLOCKS);

    // ---- Phase B: qW ----
    {
        int ci = tid & 15, g = tid >> 4;                       // c-offset, d-group
        int h = b >> 5;
        int c = ((b & 31) << 4) + ci;
        int d0 = g * 8;
        float acc = 0.f;
#pragma unroll
        for (int dd = 0; dd < 8; ++dd) {
            int hd = h * DD + d0 + dd;
            acc += q[hd] * Wk[(size_t)hd * CC + c];
        }
        __shared__ float redB[16][17];
        redB[g][ci] = acc;
        __syncthreads();
        if (g == 0) {
            float s = 0.f;
#pragma unroll
            for (int k = 0; k < 16; ++k) s += redB[k][ci];
            qW[h * CC + c] = s;
        }
    }
    grid_barrier(cnt + 16, FRONT_BLOCKS);

    // ---- Phase C: scores ----
    {
        const float scale = 0.08838834764831845f;              // 1/sqrt(128)
        const float4* qr = (const float4*)(qW + wv * CC);
        int c4a = lane * 2, c4b = c4a + 1;
        float4 wa = qr[c4a], wb = qr[c4b];
        for (int n = b; n < NN; n += FRONT_BLOCKS) {
            const float4* xr = (const float4*)(x + (size_t)n * CC);
            float4 xa = xr[c4a], xb = xr[c4b];
            float acc = xa.x * wa.x + xa.y * wa.y + xa.z * wa.z + xa.w * wa.w +
                        xb.x * wb.x + xb.y * wb.y + xb.z * wb.z + xb.w * wb.w;
#pragma unroll
            for (int off = 32; off; off >>= 1) acc += __shfl_xor(acc, off);
            if (lane == 0) sc[wv * NN + n] = scale * acc;
        }
    }

    // ---- tail: last block through C does select ----
    __shared__ int lastFlag;
    __threadfence();
    __syncthreads();
    if (tid == 0) {
        int r = __hip_atomic_fetch_add(cnt + 32, 1, __ATOMIC_ACQ_REL, __HIP_MEMORY_SCOPE_AGENT);
        lastFlag = (r == FRONT_BLOCKS - 1);
    }
    __syncthreads();
    if (!lastFlag) return;
    __threadfence();

    if (wv == 0) {
        float pw0 = 0.f, pw1 = 0.f, pw2 = 0.f, pw3 = 0.f;
#pragma unroll
        for (int h = 0; h < HH; ++h) {
            float s0 = sc[h * NN + lane];
            float s1 = sc[h * NN + lane + 64];
            float s2 = sc[h * NN + lane + 128];
            float s3 = (lane + 192 < NN) ? sc[h * NN + lane + 192] : -1e30f;
            float m = fmaxf(fmaxf(s0, s1), fmaxf(s2, s3));
#pragma unroll
            for (int off = 32; off; off >>= 1) m = fmaxf(m, __shfl_xor(m, off));
            float e0 = expf(s0 - m), e1 = expf(s1 - m), e2 = expf(s2 - m);
            float e3 = (lane + 192 < NN) ? expf(s3 - m) : 0.f;
            float ss = e0 + e1 + e2 + e3;
#pragma unroll
            for (int off = 32; off; off >>= 1) ss += __shfl_xor(ss, off);
            float inv = 1.f / ss;
            pw0 += e0 * inv; pw1 += e1 * inv; pw2 += e2 * inv; pw3 += e3 * inv;
        }
        float v0 = pw0, v1 = pw1, v2 = pw2;
        float v3 = (lane + 192 < NN) ? pw3 : -2e30f;
        int p = -1;
        for (int r = 0; r < TOPM; ++r) {
            float v = -3e30f; int idx = -1;
            if (v0 >= v) { v = v0; idx = lane; }
            if (v1 >= v) { v = v1; idx = lane + 64; }
            if (v2 >= v) { v = v2; idx = lane + 128; }
            if (v3 >= v) { v = v3; idx = lane + 192; }
#pragma unroll
            for (int off = 32; off; off >>= 1) {
                float vo = __shfl_xor(v, off);
                int   io = __shfl_xor(idx, off);
                if (vo > v || (vo == v && io > idx)) { v = vo; idx = io; }
            }
            if ((idx & 63) == lane) {
                int jj = idx >> 6;
                if (jj == 0) v0 = -2e30f;
                else if (jj == 1) v1 = -2e30f;
                else if (jj == 2) v2 = -2e30f;
                else v3 = -2e30f;
            }
            if (idx > p) p = idx;
        }
        if (lane == 0) *(int*)(ws + WS_P) = p;
    }
}

// ---------------------------------------------------------------------------
// Broadcast: out0[b,t,m,c] = x[b,t,p,c]; out1 identical right after.
// Pure gather-copy; 1 float4 load + 20 float4 stores per thread.
// ---------------------------------------------------------------------------
__global__ void __launch_bounds__(256) k_bcast(
        const float* __restrict__ x, const float* __restrict__ ws,
        float* __restrict__ out) {
    int p = *(const int*)(ws + WS_P);
    int gt = blockIdx.x * 256 + threadIdx.x;        // 0 .. BB*TT*128-1
    int bt = gt >> 7;
    int c4 = gt & 127;
    float4 v = ((const float4*)x)[((size_t)bt * NN + p) * 128 + c4];
    float4* o0 = (float4*)out + ((size_t)bt * TOPM) * 128 + c4;
    float4* o1 = o0 + (size_t)BB * TT * TOPM * 128;
#pragma unroll
    for (int m = 0; m < TOPM; ++m) {
        o0[(size_t)m * 128] = v;
        o1[(size_t)m * 128] = v;
    }
}

extern "C" void kernel_launch(void* const* d_in, const int* in_sizes, int n_in,
                              void* d_out, int out_size, void* d_ws, size_t ws_size,
                              hipStream_t stream) {
    const float* x   = (const float*)d_in[0];   // (16,60,196,512)
    const float* qst = (const float*)d_in[1];   // (16,512)
    const float* Wq  = (const float*)d_in[2];   // (512,512)
    const float* bq  = (const float*)d_in[3];   // (512,)
    const float* Wk  = (const float*)d_in[4];   // (512,512)
    // bk (d_in[5]) unused: per-head constant cancels in softmax over n

    float* ws = (float*)d_ws;

    // zero the barrier counters (first 256 bytes) every call
    hipMemsetAsync(d_ws, 0, 256, stream);
    k_front<<<FRONT_BLOCKS, 256, 0, stream>>>(x, qst, Wq, bq, Wk, ws);
    k_bcast<<<(BB * TT * 128) / 256, 256, 0, stream>>>(x, ws, (float*)d_out);
}

// Round 4
// 43.412 us; speedup vs baseline: 1.9140x; 1.9140x over previous
//
#include <hip/hip_runtime.h>
#include <math.h>

#define BB 16
#define TT 60
#define NN 196
#define CC 512
#define HH 4
#define DD 128
#define TOPM 10

__device__ __forceinline__ float hsum4(float4 v) { return v.x + v.y + v.z + v.w; }

// ---------------------------------------------------------------------------
// K_front: 16 blocks x 512 threads. Block b -> (h = b&3, g = b>>2).
// Entirely block-local (no grid sync):
//   A: q[h,d] = qst[0,:]·Wq[h*128+d,:] + bq   (d-parallel, e-split 4-way)
//   B: qW[h,c] = sum_d q[h,d]*Wk[h*128+d,c]   (c-parallel, d-split 4-way)
//   C: sc[h,n] = scale * qW[h,:]·x[0,0,n,:]   for n in [g*49, g*49+49)
// q and qW live only in LDS; only sc (784 floats) goes to global ws.
// (bk bias dropped: per-head constant cancels in softmax over n)
// ---------------------------------------------------------------------------
__global__ void __launch_bounds__(512) k_front(
        const float* __restrict__ x, const float* __restrict__ qst,
        const float* __restrict__ Wq, const float* __restrict__ bq,
        const float* __restrict__ Wk, float* __restrict__ sc) {
    __shared__ float4 pbuf[4][132];      // padded partial buffer (reused A/B)
    __shared__ float  qh[DD];
    __shared__ float  qWs[CC];

    int b = blockIdx.x, t = threadIdx.x;
    int h = b & 3, g = b >> 2;

    // ---- Phase A: q[h, 0..127] ----
    {
        int d = t >> 2, qq = t & 3;      // d-owner, e-quarter
        const float4* row = (const float4*)(Wq + (size_t)(h * DD + d) * CC);
        const float4* qs  = (const float4*)qst;   // b=0 row of qst
        float4 a = make_float4(0.f, 0.f, 0.f, 0.f);
        int e0 = qq * 32;
#pragma unroll 8
        for (int i = 0; i < 32; ++i) {
            float4 w = row[e0 + i], v = qs[e0 + i];
            a.x += w.x * v.x; a.y += w.y * v.y; a.z += w.z * v.z; a.w += w.w * v.w;
        }
        pbuf[qq][d] = a;
    }
    __syncthreads();
    if (t < DD)
        qh[t] = hsum4(pbuf[0][t]) + hsum4(pbuf[1][t]) + hsum4(pbuf[2][t]) +
                hsum4(pbuf[3][t]) + bq[h * DD + t];
    __syncthreads();

    // ---- Phase B: qW[h, 0..511] ----
    {
        int c4 = t & 127, dg = t >> 7;   // float4-column owner, d-group
        const float4* wk = (const float4*)(Wk + (size_t)(h * DD + dg * 32) * CC);
        float4 a = make_float4(0.f, 0.f, 0.f, 0.f);
#pragma unroll 8
        for (int i = 0; i < 32; ++i) {
            float qv = qh[dg * 32 + i];                 // wave-uniform broadcast
            float4 w = wk[(size_t)i * (CC / 4) + c4];   // coalesced row segment
            a.x += qv * w.x; a.y += qv * w.y; a.z += qv * w.z; a.w += qv * w.w;
        }
        pbuf[dg][c4] = a;
    }
    __syncthreads();
    if (t < 128) {
        float4 s0 = pbuf[0][t], s1 = pbuf[1][t], s2 = pbuf[2][t], s3 = pbuf[3][t];
        float4 r;
        r.x = s0.x + s1.x + s2.x + s3.x;
        r.y = s0.y + s1.y + s2.y + s3.y;
        r.z = s0.z + s1.z + s2.z + s3.z;
        r.w = s0.w + s1.w + s2.w + s3.w;
        ((float4*)qWs)[t] = r;
    }
    __syncthreads();

    // ---- Phase C: scores for this block's 49 n's ----
    {
        int wv = t >> 6, lane = t & 63;
        const float scale = 0.08838834764831845f;       // 1/sqrt(128)
        const float4* qw4 = (const float4*)qWs;
        float4 wa = qw4[lane * 2], wb = qw4[lane * 2 + 1];
        for (int i = wv; i < 49; i += 8) {
            int n = g * 49 + i;
            const float4* xr = (const float4*)(x + (size_t)n * CC);  // x[0,0,n,:]
            float4 xa = xr[lane * 2], xb = xr[lane * 2 + 1];
            float acc = xa.x * wa.x + xa.y * wa.y + xa.z * wa.z + xa.w * wa.w +
                        xb.x * wb.x + xb.y * wb.y + xb.z * wb.z + xb.w * wb.w;
#pragma unroll
            for (int off = 32; off; off >>= 1) acc += __shfl_xor(acc, off);
            if (lane == 0) sc[h * NN + n] = scale * acc;
        }
    }
}

// ---------------------------------------------------------------------------
// K_bcast_sel (proven in round 2): wave 0 of every block redundantly
// recomputes p from the 784 scores (L2-broadcast): per-head softmax, mean
// over heads, top-10, p = max index among the 10 winners. Then all threads
// copy x[b,t,p,:] into both outputs.
// ---------------------------------------------------------------------------
__global__ void __launch_bounds__(256) k_bcast_sel(
        const float* __restrict__ x, const float* __restrict__ sc,
        float* __restrict__ out) {
    __shared__ int sp;
    int tid = threadIdx.x;

    if (tid < 64) {
        int lane = tid;
        float pw0 = 0.f, pw1 = 0.f, pw2 = 0.f, pw3 = 0.f;
#pragma unroll
        for (int h = 0; h < HH; ++h) {
            float s0 = sc[h * NN + lane];
            float s1 = sc[h * NN + lane + 64];
            float s2 = sc[h * NN + lane + 128];
            float s3 = (lane + 192 < NN) ? sc[h * NN + lane + 192] : -1e30f;
            float m = fmaxf(fmaxf(s0, s1), fmaxf(s2, s3));
#pragma unroll
            for (int off = 32; off; off >>= 1) m = fmaxf(m, __shfl_xor(m, off));
            float e0 = expf(s0 - m), e1 = expf(s1 - m), e2 = expf(s2 - m);
            float e3 = (lane + 192 < NN) ? expf(s3 - m) : 0.f;
            float ss = e0 + e1 + e2 + e3;
#pragma unroll
            for (int off = 32; off; off >>= 1) ss += __shfl_xor(ss, off);
            float inv = 1.f / ss;
            pw0 += e0 * inv; pw1 += e1 * inv; pw2 += e2 * inv; pw3 += e3 * inv;
        }
        float v0 = pw0, v1 = pw1, v2 = pw2;
        float v3 = (lane + 192 < NN) ? pw3 : -2e30f;
        int p = -1;
        for (int r = 0; r < TOPM; ++r) {
            float v = -3e30f; int idx = -1;
            if (v0 >= v) { v = v0; idx = lane; }
            if (v1 >= v) { v = v1; idx = lane + 64; }
            if (v2 >= v) { v = v2; idx = lane + 128; }
            if (v3 >= v) { v = v3; idx = lane + 192; }
#pragma unroll
            for (int off = 32; off; off >>= 1) {
                float vo = __shfl_xor(v, off);
                int   io = __shfl_xor(idx, off);
                if (vo > v || (vo == v && io > idx)) { v = vo; idx = io; }
            }
            if ((idx & 63) == lane) {
                int jj = idx >> 6;
                if (jj == 0) v0 = -2e30f;
                else if (jj == 1) v1 = -2e30f;
                else if (jj == 2) v2 = -2e30f;
                else v3 = -2e30f;
            }
            if (idx > p) p = idx;
        }
        if (lane == 0) sp = p;
    }
    __syncthreads();
    int p = sp;

    int gt = blockIdx.x * 256 + tid;                // 0 .. BB*TT*128-1
    int bt = gt >> 7;
    int c4 = gt & 127;
    float4 v = ((const float4*)x)[((size_t)bt * NN + p) * 128 + c4];
    float4* o0 = (float4*)out + ((size_t)bt * TOPM) * 128 + c4;
    float4* o1 = o0 + (size_t)BB * TT * TOPM * 128;
#pragma unroll
    for (int m = 0; m < TOPM; ++m) {
        o0[(size_t)m * 128] = v;
        o1[(size_t)m * 128] = v;
    }
}

extern "C" void kernel_launch(void* const* d_in, const int* in_sizes, int n_in,
                              void* d_out, int out_size, void* d_ws, size_t ws_size,
                              hipStream_t stream) {
    const float* x   = (const float*)d_in[0];   // (16,60,196,512)
    const float* qst = (const float*)d_in[1];   // (16,512)
    const float* Wq  = (const float*)d_in[2];   // (512,512)
    const float* bq  = (const float*)d_in[3];   // (512,)
    const float* Wk  = (const float*)d_in[4];   // (512,512)
    // bk (d_in[5]) unused: per-head constant cancels in softmax over n

    float* sc = (float*)d_ws;                   // 784 floats, fully rewritten each call

    k_front    <<<16, 512, 0, stream>>>(x, qst, Wq, bq, Wk, sc);
    k_bcast_sel<<<(BB * TT * 128) / 256, 256, 0, stream>>>(x, sc, (float*)d_out);
}

// Round 5
// 33.161 us; speedup vs baseline: 2.5056x; 1.3091x over previous
//
#include <hip/hip_runtime.h>
#include <math.h>

#define BB 16
#define TT 60
#define NN 196
#define CC 512
#define HH 4
#define DD 128
#define TOPM 10
#define NPG 49            // n's per front block
#define SCALE 0.08838834764831845f   // 1/sqrt(128)

// ---------------------------------------------------------------------------
// k_front: 256 blocks x 256 threads. Block b -> (h = b&3, dg = (b>>2)&15,
// ng = b>>6). Block-local, no cross-block dependency:
//   A: qs[r]   = scale * (qst[0,:]·Wq[h*128+dg*8+r, :] + bq)   r=0..7
//   B: u[c]    = sum_{r<8} qs[r] * Wk[h*128+dg*8+r, c]          c=0..511
//   C: sp[h,dg,n] = u[:]·x[0,0,n,:]   for n in [ng*49, ng*49+49)
// sp are d-partial scores; summed deterministically in k_bcast_sel.
// (bk dropped: per-head constant cancels in softmax over n)
// ---------------------------------------------------------------------------
__global__ void __launch_bounds__(256) k_front(
        const float* __restrict__ x, const float* __restrict__ qst,
        const float* __restrict__ Wq, const float* __restrict__ bq,
        const float* __restrict__ Wk, float* __restrict__ sp) {
    __shared__ float  qs[8];
    __shared__ float4 upart[2][128];
    __shared__ float4 u4[128];

    int b = blockIdx.x, t = threadIdx.x;
    int h = b & 3, dg = (b >> 2) & 15, ng = b >> 6;
    int row0 = h * DD + dg * 8;

    // ---- Phase A: 8 q values (32 threads per row) ----
    {
        int r = t >> 5, l = t & 31;
        const float4* wrow = (const float4*)(Wq + (size_t)(row0 + r) * CC);
        const float4* qv4  = (const float4*)qst;          // qst row b=0
        float acc = 0.f;
#pragma unroll
        for (int j = 0; j < 4; ++j) {
            float4 w = wrow[l + 32 * j], v = qv4[l + 32 * j];
            acc += w.x * v.x + w.y * v.y + w.z * v.z + w.w * v.w;
        }
#pragma unroll
        for (int off = 16; off; off >>= 1) acc += __shfl_xor(acc, off, 32);
        if (l == 0) qs[r] = (acc + bq[row0 + r]) * SCALE;
    }
    __syncthreads();

    // ---- Phase B: partial u[512] over this block's 8 d's ----
    {
        int c4 = t & 127, half = t >> 7;                  // col, row-half
        float4 a = make_float4(0.f, 0.f, 0.f, 0.f);
#pragma unroll
        for (int i = 0; i < 4; ++i) {
            int r = half * 4 + i;
            float qv = qs[r];                             // LDS broadcast
            float4 w = ((const float4*)Wk)[(size_t)(row0 + r) * 128 + c4];
            a.x += qv * w.x; a.y += qv * w.y; a.z += qv * w.z; a.w += qv * w.w;
        }
        upart[half][c4] = a;
    }
    __syncthreads();
    if (t < 128) {
        float4 a = upart[0][t], bb = upart[1][t];
        u4[t] = make_float4(a.x + bb.x, a.y + bb.y, a.z + bb.z, a.w + bb.w);
    }
    __syncthreads();

    // ---- Phase C: partial scores for 49 n's ----
    {
        int wv = t >> 6, lane = t & 63;
        float4 ua = u4[lane * 2], ub = u4[lane * 2 + 1];
        for (int i = wv; i < NPG; i += 4) {
            int n = ng * NPG + i;
            const float4* xr = (const float4*)(x + (size_t)n * CC);  // x[0,0,n,:]
            float4 xa = xr[lane * 2], xb = xr[lane * 2 + 1];
            float acc = xa.x * ua.x + xa.y * ua.y + xa.z * ua.z + xa.w * ua.w +
                        xb.x * ub.x + xb.y * ub.y + xb.z * ub.z + xb.w * ub.w;
#pragma unroll
            for (int off = 32; off; off >>= 1) acc += __shfl_xor(acc, off);
            if (lane == 0) sp[(h * 16 + dg) * NN + n] = acc;
        }
    }
}

// ---------------------------------------------------------------------------
// k_bcast_sel: preamble (per block, redundant, L2-hot):
//   wave h: sc[h,n] = sum_{dg<16} sp[h,dg,n]  (fixed order, deterministic),
//           softmax over n -> att[h][n] in LDS
//   wave 0: pw[n] = mean_h att, top-10, p = max index among winners
// Then all 256 threads gather x[b,t,p,:] and write both outputs.
// ---------------------------------------------------------------------------
__global__ void __launch_bounds__(256) k_bcast_sel(
        const float* __restrict__ x, const float* __restrict__ sp,
        float* __restrict__ out) {
    __shared__ float att[HH][NN];
    __shared__ int spi;
    int t = threadIdx.x, wv = t >> 6, lane = t & 63;

    {   // per-head partial-sum + softmax (wave wv handles head wv)
        const float* base = sp + wv * 16 * NN;
        float s0 = 0.f, s1 = 0.f, s2 = 0.f, s3 = 0.f;
#pragma unroll
        for (int dg = 0; dg < 16; ++dg) {
            const float* r = base + dg * NN;
            s0 += r[lane]; s1 += r[lane + 64]; s2 += r[lane + 128];
            if (lane < 4) s3 += r[lane + 192];
        }
        float s3m = (lane < 4) ? s3 : -1e30f;
        float m = fmaxf(fmaxf(s0, s1), fmaxf(s2, s3m));
#pragma unroll
        for (int off = 32; off; off >>= 1) m = fmaxf(m, __shfl_xor(m, off));
        float e0 = expf(s0 - m), e1 = expf(s1 - m), e2 = expf(s2 - m);
        float e3 = (lane < 4) ? expf(s3 - m) : 0.f;
        float ss = e0 + e1 + e2 + e3;
#pragma unroll
        for (int off = 32; off; off >>= 1) ss += __shfl_xor(ss, off);
        float inv = 1.f / ss;
        att[wv][lane] = e0 * inv;
        att[wv][lane + 64] = e1 * inv;
        att[wv][lane + 128] = e2 * inv;
        if (lane < 4) att[wv][lane + 192] = e3 * inv;
    }
    __syncthreads();

    if (wv == 0) {
        float v0 = 0.25f * (att[0][lane] + att[1][lane] + att[2][lane] + att[3][lane]);
        float v1 = 0.25f * (att[0][lane + 64] + att[1][lane + 64] + att[2][lane + 64] + att[3][lane + 64]);
        float v2 = 0.25f * (att[0][lane + 128] + att[1][lane + 128] + att[2][lane + 128] + att[3][lane + 128]);
        float v3 = (lane < 4)
            ? 0.25f * (att[0][lane + 192] + att[1][lane + 192] + att[2][lane + 192] + att[3][lane + 192])
            : -2e30f;
        int p = -1;
        for (int r = 0; r < TOPM; ++r) {
            float v = -3e30f; int idx = -1;
            if (v0 >= v) { v = v0; idx = lane; }
            if (v1 >= v) { v = v1; idx = lane + 64; }
            if (v2 >= v) { v = v2; idx = lane + 128; }
            if (v3 >= v) { v = v3; idx = lane + 192; }
#pragma unroll
            for (int off = 32; off; off >>= 1) {
                float vo = __shfl_xor(v, off);
                int   io = __shfl_xor(idx, off);
                if (vo > v || (vo == v && io > idx)) { v = vo; idx = io; }
            }
            if ((idx & 63) == lane) {
                int jj = idx >> 6;
                if (jj == 0) v0 = -2e30f;
                else if (jj == 1) v1 = -2e30f;
                else if (jj == 2) v2 = -2e30f;
                else v3 = -2e30f;
            }
            if (idx > p) p = idx;
        }
        if (lane == 0) spi = p;
    }
    __syncthreads();
    int p = spi;

    int gt = blockIdx.x * 256 + t;                  // 0 .. BB*TT*128-1
    int bt = gt >> 7;
    int c4 = gt & 127;
    float4 v = ((const float4*)x)[((size_t)bt * NN + p) * 128 + c4];
    float4* o0 = (float4*)out + ((size_t)bt * TOPM) * 128 + c4;
    float4* o1 = o0 + (size_t)BB * TT * TOPM * 128;
#pragma unroll
    for (int m = 0; m < TOPM; ++m) {
        o0[(size_t)m * 128] = v;
        o1[(size_t)m * 128] = v;
    }
}

extern "C" void kernel_launch(void* const* d_in, const int* in_sizes, int n_in,
                              void* d_out, int out_size, void* d_ws, size_t ws_size,
                              hipStream_t stream) {
    const float* x   = (const float*)d_in[0];   // (16,60,196,512)
    const float* qst = (const float*)d_in[1];   // (16,512)
    const float* Wq  = (const float*)d_in[2];   // (512,512)
    const float* bq  = (const float*)d_in[3];   // (512,)
    const float* Wk  = (const float*)d_in[4];   // (512,512)
    // bk (d_in[5]) unused: per-head constant cancels in softmax over n

    float* sp = (float*)d_ws;                   // 4*16*196 floats (~50 KB), fully
                                                // rewritten by k_front every call

    k_front    <<<256, 256, 0, stream>>>(x, qst, Wq, bq, Wk, sp);
    k_bcast_sel<<<(BB * TT * 128) / 256, 256, 0, stream>>>(x, sp, (float*)d_out);
}

// Round 6
// 32.232 us; speedup vs baseline: 2.5778x; 1.0288x over previous
//
#include <hip/hip_runtime.h>
#include <math.h>

#define BB 16
#define TT 60
#define NN 196
#define CC 512
#define HH 4
#define DD 128
#define TOPM 10
#define NPG 49                        // n's per front block
#define SCALE 0.08838834764831845f    // 1/sqrt(128)

typedef float f32x4 __attribute__((ext_vector_type(4)));

// ws layout (floats): sp[4*16*196] partial scores; then p (int) at WS_P.
#define WS_P (HH * 16 * NN)

// ---------------------------------------------------------------------------
// k_front (proven in R5): 256 blocks x 256 threads. Block b -> (h = b&3,
// dg = (b>>2)&15, ng = b>>6). Block-local, no cross-block dependency:
//   A: qs[r]      = scale * (qst[0,:]·Wq[h*128+dg*8+r, :] + bq)   r=0..7
//   B: u[c]       = sum_{r<8} qs[r] * Wk[h*128+dg*8+r, c]
//   C: sp[h,dg,n] = u[:]·x[0,0,n,:]   for n in [ng*49, (ng+1)*49)
// (bk dropped: per-head constant cancels in softmax over n)
// ---------------------------------------------------------------------------
__global__ void __launch_bounds__(256) k_front(
        const float* __restrict__ x, const float* __restrict__ qst,
        const float* __restrict__ Wq, const float* __restrict__ bq,
        const float* __restrict__ Wk, float* __restrict__ sp) {
    __shared__ float  qs[8];
    __shared__ float4 upart[2][128];
    __shared__ float4 u4[128];

    int b = blockIdx.x, t = threadIdx.x;
    int h = b & 3, dg = (b >> 2) & 15, ng = b >> 6;
    int row0 = h * DD + dg * 8;

    // ---- Phase A: 8 q values (32 threads per row) ----
    {
        int r = t >> 5, l = t & 31;
        const float4* wrow = (const float4*)(Wq + (size_t)(row0 + r) * CC);
        const float4* qv4  = (const float4*)qst;          // qst row b=0
        float acc = 0.f;
#pragma unroll
        for (int j = 0; j < 4; ++j) {
            float4 w = wrow[l + 32 * j], v = qv4[l + 32 * j];
            acc += w.x * v.x + w.y * v.y + w.z * v.z + w.w * v.w;
        }
#pragma unroll
        for (int off = 16; off; off >>= 1) acc += __shfl_xor(acc, off, 32);
        if (l == 0) qs[r] = (acc + bq[row0 + r]) * SCALE;
    }
    __syncthreads();

    // ---- Phase B: partial u[512] over this block's 8 d's ----
    {
        int c4 = t & 127, half = t >> 7;
        float4 a = make_float4(0.f, 0.f, 0.f, 0.f);
#pragma unroll
        for (int i = 0; i < 4; ++i) {
            int r = half * 4 + i;
            float qv = qs[r];
            float4 w = ((const float4*)Wk)[(size_t)(row0 + r) * 128 + c4];
            a.x += qv * w.x; a.y += qv * w.y; a.z += qv * w.z; a.w += qv * w.w;
        }
        upart[half][c4] = a;
    }
    __syncthreads();
    if (t < 128) {
        float4 a = upart[0][t], bb = upart[1][t];
        u4[t] = make_float4(a.x + bb.x, a.y + bb.y, a.z + bb.z, a.w + bb.w);
    }
    __syncthreads();

    // ---- Phase C: partial scores for 49 n's ----
    {
        int wv = t >> 6, lane = t & 63;
        float4 ua = u4[lane * 2], ub = u4[lane * 2 + 1];
        for (int i = wv; i < NPG; i += 4) {
            int n = ng * NPG + i;
            const float4* xr = (const float4*)(x + (size_t)n * CC);  // x[0,0,n,:]
            float4 xa = xr[lane * 2], xb = xr[lane * 2 + 1];
            float acc = xa.x * ua.x + xa.y * ua.y + xa.z * ua.z + xa.w * ua.w +
                        xb.x * ub.x + xb.y * ub.y + xb.z * ub.z + xb.w * ub.w;
#pragma unroll
            for (int off = 32; off; off >>= 1) acc += __shfl_xor(acc, off);
            if (lane == 0) sp[(h * 16 + dg) * NN + n] = acc;
        }
    }
}

// ---------------------------------------------------------------------------
// k_select: ONE block, 256 threads. Wave h: sc[h,n] = sum_dg sp[h,dg,n]
// (fixed order, deterministic), softmax over n -> att[h][:] in LDS.
// Wave 0: pw = mean_h att, top-10, p = max index among winners -> ws[WS_P].
// ---------------------------------------------------------------------------
__global__ void __launch_bounds__(256) k_select(
        const float* __restrict__ sp, int* __restrict__ pOut) {
    __shared__ float att[HH][NN];
    int t = threadIdx.x, wv = t >> 6, lane = t & 63;

    {   // per-head partial-sum + softmax (wave wv handles head wv)
        const float* base = sp + wv * 16 * NN;
        float s0 = 0.f, s1 = 0.f, s2 = 0.f, s3 = 0.f;
#pragma unroll
        for (int dg = 0; dg < 16; ++dg) {
            const float* r = base + dg * NN;
            s0 += r[lane]; s1 += r[lane + 64]; s2 += r[lane + 128];
            if (lane < 4) s3 += r[lane + 192];
        }
        float s3m = (lane < 4) ? s3 : -1e30f;
        float m = fmaxf(fmaxf(s0, s1), fmaxf(s2, s3m));
#pragma unroll
        for (int off = 32; off; off >>= 1) m = fmaxf(m, __shfl_xor(m, off));
        float e0 = expf(s0 - m), e1 = expf(s1 - m), e2 = expf(s2 - m);
        float e3 = (lane < 4) ? expf(s3 - m) : 0.f;
        float ss = e0 + e1 + e2 + e3;
#pragma unroll
        for (int off = 32; off; off >>= 1) ss += __shfl_xor(ss, off);
        float inv = 1.f / ss;
        att[wv][lane] = e0 * inv;
        att[wv][lane + 64] = e1 * inv;
        att[wv][lane + 128] = e2 * inv;
        if (lane < 4) att[wv][lane + 192] = e3 * inv;
    }
    __syncthreads();

    if (wv == 0) {
        float v0 = 0.25f * (att[0][lane] + att[1][lane] + att[2][lane] + att[3][lane]);
        float v1 = 0.25f * (att[0][lane + 64] + att[1][lane + 64] + att[2][lane + 64] + att[3][lane + 64]);
        float v2 = 0.25f * (att[0][lane + 128] + att[1][lane + 128] + att[2][lane + 128] + att[3][lane + 128]);
        float v3 = (lane < 4)
            ? 0.25f * (att[0][lane + 192] + att[1][lane + 192] + att[2][lane + 192] + att[3][lane + 192])
            : -2e30f;
        int p = -1;
        for (int r = 0; r < TOPM; ++r) {
            float v = -3e30f; int idx = -1;
            if (v0 >= v) { v = v0; idx = lane; }
            if (v1 >= v) { v = v1; idx = lane + 64; }
            if (v2 >= v) { v = v2; idx = lane + 128; }
            if (v3 >= v) { v = v3; idx = lane + 192; }
#pragma unroll
            for (int off = 32; off; off >>= 1) {
                float vo = __shfl_xor(v, off);
                int   io = __shfl_xor(idx, off);
                if (vo > v || (vo == v && io > idx)) { v = vo; idx = io; }
            }
            if ((idx & 63) == lane) {
                int jj = idx >> 6;
                if (jj == 0) v0 = -2e30f;
                else if (jj == 1) v1 = -2e30f;
                else if (jj == 2) v2 = -2e30f;
                else v3 = -2e30f;
            }
            if (idx > p) p = idx;
        }
        if (lane == 0) *pOut = p;
    }
}

// ---------------------------------------------------------------------------
// k_copy: pure gather + broadcast. One scalar p load, one float4 gather,
// 20 nontemporal float4 stores (skip L2 write-allocate for 39 MB stream).
// out0[b,t,m,c] = x[b,t,p,c]; out1 identical, concatenated right after.
// ---------------------------------------------------------------------------
__global__ void __launch_bounds__(256) k_copy(
        const float* __restrict__ x, const int* __restrict__ pPtr,
        float* __restrict__ out) {
    int p = *pPtr;
    int gt = blockIdx.x * 256 + threadIdx.x;        // 0 .. BB*TT*128-1
    int bt = gt >> 7;
    int c4 = gt & 127;
    f32x4 v = ((const f32x4*)x)[((size_t)bt * NN + p) * 128 + c4];
    f32x4* o0 = (f32x4*)out + ((size_t)bt * TOPM) * 128 + c4;
    f32x4* o1 = o0 + (size_t)BB * TT * TOPM * 128;
#pragma unroll
    for (int m = 0; m < TOPM; ++m) {
        __builtin_nontemporal_store(v, o0 + (size_t)m * 128);
        __builtin_nontemporal_store(v, o1 + (size_t)m * 128);
    }
}

extern "C" void kernel_launch(void* const* d_in, const int* in_sizes, int n_in,
                              void* d_out, int out_size, void* d_ws, size_t ws_size,
                              hipStream_t stream) {
    const float* x   = (const float*)d_in[0];   // (16,60,196,512)
    const float* qst = (const float*)d_in[1];   // (16,512)
    const float* Wq  = (const float*)d_in[2];   // (512,512)
    const float* bq  = (const float*)d_in[3];   // (512,)
    const float* Wk  = (const float*)d_in[4];   // (512,512)
    // bk (d_in[5]) unused: per-head constant cancels in softmax over n

    float* sp = (float*)d_ws;                   // 4*16*196 floats, fully
                                                // rewritten by k_front each call
    int*   p  = (int*)(sp + WS_P);

    k_front <<<256, 256, 0, stream>>>(x, qst, Wq, bq, Wk, sp);
    k_select<<<1,   256, 0, stream>>>(sp, p);
    k_copy  <<<(BB * TT * 128) / 256, 256, 0, stream>>>(x, p, (float*)d_out);
}

// Round 7
// 32.182 us; speedup vs baseline: 2.5818x; 1.0015x over previous
//
#include <hip/hip_runtime.h>
#include <math.h>

#define BB 16
#define TT 60
#define NN 196
#define CC 512
#define HH 4
#define DD 128
#define TOPM 10
#define NPG 49                        // n's per front block
#define SCALE 0.08838834764831845f    // 1/sqrt(128)

typedef float f32x4 __attribute__((ext_vector_type(4)));

// ws layout (floats): sp[4*16*196] partial scores; then p (int) at WS_P.
#define WS_P (HH * 16 * NN)

// ---------------------------------------------------------------------------
// k_front (unchanged from R5/R6): 256 blocks x 256 threads. Block b ->
// (h = b&3, dg = (b>>2)&15, ng = b>>6). Block-local, no cross-block deps:
//   A: qs[r]      = scale * (qst[0,:]·Wq[h*128+dg*8+r, :] + bq)   r=0..7
//   B: u[c]       = sum_{r<8} qs[r] * Wk[h*128+dg*8+r, c]
//   C: sp[h,dg,n] = u[:]·x[0,0,n,:]   for n in [ng*49, (ng+1)*49)
// (bk dropped: per-head constant cancels in softmax over n)
// ---------------------------------------------------------------------------
__global__ void __launch_bounds__(256) k_front(
        const float* __restrict__ x, const float* __restrict__ qst,
        const float* __restrict__ Wq, const float* __restrict__ bq,
        const float* __restrict__ Wk, float* __restrict__ sp) {
    __shared__ float  qs[8];
    __shared__ float4 upart[2][128];
    __shared__ float4 u4[128];

    int b = blockIdx.x, t = threadIdx.x;
    int h = b & 3, dg = (b >> 2) & 15, ng = b >> 6;
    int row0 = h * DD + dg * 8;

    // ---- Phase A: 8 q values (32 threads per row) ----
    {
        int r = t >> 5, l = t & 31;
        const float4* wrow = (const float4*)(Wq + (size_t)(row0 + r) * CC);
        const float4* qv4  = (const float4*)qst;          // qst row b=0
        float acc = 0.f;
#pragma unroll
        for (int j = 0; j < 4; ++j) {
            float4 w = wrow[l + 32 * j], v = qv4[l + 32 * j];
            acc += w.x * v.x + w.y * v.y + w.z * v.z + w.w * v.w;
        }
#pragma unroll
        for (int off = 16; off; off >>= 1) acc += __shfl_xor(acc, off, 32);
        if (l == 0) qs[r] = (acc + bq[row0 + r]) * SCALE;
    }
    __syncthreads();

    // ---- Phase B: partial u[512] over this block's 8 d's ----
    {
        int c4 = t & 127, half = t >> 7;
        float4 a = make_float4(0.f, 0.f, 0.f, 0.f);
#pragma unroll
        for (int i = 0; i < 4; ++i) {
            int r = half * 4 + i;
            float qv = qs[r];
            float4 w = ((const float4*)Wk)[(size_t)(row0 + r) * 128 + c4];
            a.x += qv * w.x; a.y += qv * w.y; a.z += qv * w.z; a.w += qv * w.w;
        }
        upart[half][c4] = a;
    }
    __syncthreads();
    if (t < 128) {
        float4 a = upart[0][t], bb = upart[1][t];
        u4[t] = make_float4(a.x + bb.x, a.y + bb.y, a.z + bb.z, a.w + bb.w);
    }
    __syncthreads();

    // ---- Phase C: partial scores for 49 n's ----
    {
        int wv = t >> 6, lane = t & 63;
        float4 ua = u4[lane * 2], ub = u4[lane * 2 + 1];
        for (int i = wv; i < NPG; i += 4) {
            int n = ng * NPG + i;
            const float4* xr = (const float4*)(x + (size_t)n * CC);  // x[0,0,n,:]
            float4 xa = xr[lane * 2], xb = xr[lane * 2 + 1];
            float acc = xa.x * ua.x + xa.y * ua.y + xa.z * ua.z + xa.w * ua.w +
                        xb.x * ub.x + xb.y * ub.y + xb.z * ub.z + xb.w * ub.w;
#pragma unroll
            for (int off = 32; off; off >>= 1) acc += __shfl_xor(acc, off);
            if (lane == 0) sp[(h * 16 + dg) * NN + n] = acc;
        }
    }
}

// ---------------------------------------------------------------------------
// k_select (unchanged from R6): ONE block, 256 threads. Wave h: sc[h,n] =
// sum_dg sp[h,dg,n] (fixed order, deterministic), softmax -> att[h][:].
// Wave 0: pw = mean_h att, top-10, p = max index among winners.
// ---------------------------------------------------------------------------
__global__ void __launch_bounds__(256) k_select(
        const float* __restrict__ sp, int* __restrict__ pOut) {
    __shared__ float att[HH][NN];
    int t = threadIdx.x, wv = t >> 6, lane = t & 63;

    {   // per-head partial-sum + softmax (wave wv handles head wv)
        const float* base = sp + wv * 16 * NN;
        float s0 = 0.f, s1 = 0.f, s2 = 0.f, s3 = 0.f;
#pragma unroll
        for (int dg = 0; dg < 16; ++dg) {
            const float* r = base + dg * NN;
            s0 += r[lane]; s1 += r[lane + 64]; s2 += r[lane + 128];
            if (lane < 4) s3 += r[lane + 192];
        }
        float s3m = (lane < 4) ? s3 : -1e30f;
        float m = fmaxf(fmaxf(s0, s1), fmaxf(s2, s3m));
#pragma unroll
        for (int off = 32; off; off >>= 1) m = fmaxf(m, __shfl_xor(m, off));
        float e0 = expf(s0 - m), e1 = expf(s1 - m), e2 = expf(s2 - m);
        float e3 = (lane < 4) ? expf(s3 - m) : 0.f;
        float ss = e0 + e1 + e2 + e3;
#pragma unroll
        for (int off = 32; off; off >>= 1) ss += __shfl_xor(ss, off);
        float inv = 1.f / ss;
        att[wv][lane] = e0 * inv;
        att[wv][lane + 64] = e1 * inv;
        att[wv][lane + 128] = e2 * inv;
        if (lane < 4) att[wv][lane + 192] = e3 * inv;
    }
    __syncthreads();

    if (wv == 0) {
        float v0 = 0.25f * (att[0][lane] + att[1][lane] + att[2][lane] + att[3][lane]);
        float v1 = 0.25f * (att[0][lane + 64] + att[1][lane + 64] + att[2][lane + 64] + att[3][lane + 64]);
        float v2 = 0.25f * (att[0][lane + 128] + att[1][lane + 128] + att[2][lane + 128] + att[3][lane + 128]);
        float v3 = (lane < 4)
            ? 0.25f * (att[0][lane + 192] + att[1][lane + 192] + att[2][lane + 192] + att[3][lane + 192])
            : -2e30f;
        int p = -1;
        for (int r = 0; r < TOPM; ++r) {
            float v = -3e30f; int idx = -1;
            if (v0 >= v) { v = v0; idx = lane; }
            if (v1 >= v) { v = v1; idx = lane + 64; }
            if (v2 >= v) { v = v2; idx = lane + 128; }
            if (v3 >= v) { v = v3; idx = lane + 192; }
#pragma unroll
            for (int off = 32; off; off >>= 1) {
                float vo = __shfl_xor(v, off);
                int   io = __shfl_xor(idx, off);
                if (vo > v || (vo == v && io > idx)) { v = vo; idx = io; }
            }
            if ((idx & 63) == lane) {
                int jj = idx >> 6;
                if (jj == 0) v0 = -2e30f;
                else if (jj == 1) v1 = -2e30f;
                else if (jj == 2) v2 = -2e30f;
                else v3 = -2e30f;
            }
            if (idx > p) p = idx;
        }
        if (lane == 0) *pOut = p;
    }
}

// ---------------------------------------------------------------------------
// k_copy: one thread per output float4 of out0. idx -> (bt, m, c4).
// 1 coalesced gather (L2-hot, 10-way redundant across waves) + 2 NT stores
// (out0[idx], out1[idx]) laid out perfectly sequentially across the tensor.
// 4800 blocks x 256 threads = 1.23M threads for max store-stream ramp.
// ---------------------------------------------------------------------------
__global__ void __launch_bounds__(256) k_copy(
        const float* __restrict__ x, const int* __restrict__ pPtr,
        float* __restrict__ out) {
    int p = *pPtr;
    size_t idx = (size_t)blockIdx.x * 256 + threadIdx.x;   // 0 .. 16*60*10*128-1
    int c4 = (int)(idx & 127);
    int btm = (int)(idx >> 7);                             // bt*10 + m
    int bt = btm / TOPM;                                   // magic-mul division
    f32x4 v = ((const f32x4*)x)[((size_t)bt * NN + p) * 128 + c4];
    f32x4* o0 = (f32x4*)out + idx;
    f32x4* o1 = o0 + (size_t)BB * TT * TOPM * 128;
    __builtin_nontemporal_store(v, o0);
    __builtin_nontemporal_store(v, o1);
}

extern "C" void kernel_launch(void* const* d_in, const int* in_sizes, int n_in,
                              void* d_out, int out_size, void* d_ws, size_t ws_size,
                              hipStream_t stream) {
    const float* x   = (const float*)d_in[0];   // (16,60,196,512)
    const float* qst = (const float*)d_in[1];   // (16,512)
    const float* Wq  = (const float*)d_in[2];   // (512,512)
    const float* bq  = (const float*)d_in[3];   // (512,)
    const float* Wk  = (const float*)d_in[4];   // (512,512)
    // bk (d_in[5]) unused: per-head constant cancels in softmax over n

    float* sp = (float*)d_ws;                   // 4*16*196 floats, fully
                                                // rewritten by k_front each call
    int*   p  = (int*)(sp + WS_P);

    k_front <<<256, 256, 0, stream>>>(x, qst, Wq, bq, Wk, sp);
    k_select<<<1,   256, 0, stream>>>(sp, p);
    k_copy  <<<(BB * TT * TOPM * 128) / 256, 256, 0, stream>>>(x, p, (float*)d_out);
}